// Round 1
// baseline (226.555 us; speedup 1.0000x reference)
//
#include <hip/hip_runtime.h>
#include <math.h>

// x: (512, 3, 32, 32) fp32
// layer1: C=3 -> F=32, R=16, 3x3  -> (512,32,30,30)
// layer2: C=32 -> F=32, R=16, 3x3 -> (512,32,28,28)
// classifier: 25088 -> 10, then log_softmax
//
// Algebraic fusion (h1, h2 never materialized):
//   M[r1][r2]      = sum_f l1_f0[f][r1] * l2_f3[f][r2]            (16x16)
//   Wc2[n][r2][q]  = sum_f l2_f0[f][r2] * W_cls[n][f*784+q]       (10x16x784)
//
// This version: LDS cut 123KB -> ~75KB so 2 blocks/CU co-reside (all 512
// blocks resident at once; barrier stalls of one block hide under the other).
//   - s1 (16x1024, 64KB) eliminated: channel contraction fused into conv1
//     sliding window, x kept pixel-major as float4 (16KB).
//   - stage 3 (M contraction) done IN PLACE over the t1 buffer (each thread
//     owns 2 pixels for all 16 r2 -> no cross-thread hazard).
//   - t2 never materialized: conv2 output dotted into logits on the fly
//     (Wc2 is L2-resident, coalesced).

#define NT 1024

__global__ void precomp_kernel(const float* __restrict__ l1_f0,
                               const float* __restrict__ l2_f0,
                               const float* __restrict__ l2_f3,
                               const float* __restrict__ Wcls,
                               float* __restrict__ Wc2,
                               float* __restrict__ Mm) {
    int id = blockIdx.x * blockDim.x + threadIdx.x;
    if (id < 10 * 16 * 784) {
        int n = id / (16 * 784);
        int rem = id - n * (16 * 784);
        int r2 = rem / 784;
        int pix = rem - r2 * 784;
        float acc = 0.f;
#pragma unroll
        for (int f = 0; f < 32; ++f)
            acc += l2_f0[f * 16 + r2] * Wcls[n * 25088 + f * 784 + pix];
        Wc2[id] = acc;
    }
    if (id < 256) {
        int r1 = id >> 4, r2 = id & 15;
        float acc = 0.f;
#pragma unroll
        for (int f = 0; f < 32; ++f)
            acc += l1_f0[f * 16 + r1] * l2_f3[f * 16 + r2];
        Mm[id] = acc;
    }
}

__global__ __launch_bounds__(NT, 8) void fused_kernel(
    const float* __restrict__ x,
    const float* __restrict__ l1_f1, const float* __restrict__ l1_f2,
    const float* __restrict__ l1_f3,
    const float* __restrict__ l2_f1, const float* __restrict__ l2_f2,
    const float* __restrict__ Wc2, const float* __restrict__ Mm,
    const float* __restrict__ b_cls,
    float* __restrict__ out) {
    __shared__ float4 sx[1024];      // 16 KB: (x0,x1,x2,-) per pixel
    __shared__ float st[16 * 900];   // 57.6 KB: t1, then u in place
    __shared__ float sw1[144];
    __shared__ float sw2[144];
    __shared__ float sf3[48];
    __shared__ float sM[256];        // M (16x16), row-major [r1][r2]
    __shared__ float sred[16 * 10];
    __shared__ float slog[10];

    const int tid = threadIdx.x;
    const int b = blockIdx.x;

    // ---- stage A: x -> LDS (pixel-major float4) + small weights ----
    {
        const float* xb = x + b * 3072;
        float x0 = xb[tid];
        float x1 = xb[1024 + tid];
        float x2 = xb[2048 + tid];
        sx[tid] = make_float4(x0, x1, x2, 0.f);
    }
    if (tid < 48) sf3[tid] = l1_f3[tid];
    if (tid >= 64 && tid < 208) {
        int t = tid - 64;
        int r = t / 9, ij = t - r * 9;
        int i = ij / 3, j = ij - i * 3;
        sw1[t] = l1_f1[i * 16 + r] * l1_f2[j * 16 + r];
    }
    if (tid >= 256 && tid < 400) {
        int t = tid - 256;
        int r = t / 9, ij = t - r * 9;
        int i = ij / 3, j = ij - i * 3;
        sw2[t] = l2_f1[i * 16 + r] * l2_f2[j * 16 + r];
    }
    if (tid >= 512 && tid < 768) sM[tid - 512] = Mm[tid - 512];
    __syncthreads();

    // ---- stage B: t1[r][ho][wo] = conv3x3( sum_c x[c]*f3[c][r] , w1[r] )
    // s1 taps computed on the fly from sx (3x ds_read_b128 + 9 FMA / step)
    {
        const int r = tid >> 6;
        const int s = tid & 63;
        const int col = s & 31;
        const int half = s >> 5;
        if (col < 30) {
            const float f30 = sf3[r], f31 = sf3[16 + r], f32 = sf3[32 + r];
            const float* wp = &sw1[r * 9];
            float w0 = wp[0], w1 = wp[1], w2 = wp[2];
            float w3 = wp[3], w4 = wp[4], w5 = wp[5];
            float w6 = wp[6], w7 = wp[7], w8 = wp[8];
            const int ho0 = half * 15;
            const float4* xb = &sx[ho0 * 32 + col];
#define TAP(idx) ({ float4 _v = xb[(idx)]; _v.x * f30 + _v.y * f31 + _v.z * f32; })
            float a0 = TAP(0),  a1 = TAP(1),  a2 = TAP(2);
            float b0 = TAP(32), b1 = TAP(33), b2 = TAP(34);
            float* op = &st[r * 900 + ho0 * 30 + col];
#pragma unroll
            for (int step = 0; step < 15; ++step) {
                const int nb = (step + 2) * 32;
                float c0 = TAP(nb), c1 = TAP(nb + 1), c2 = TAP(nb + 2);
                float acc = w0 * a0 + w1 * a1 + w2 * a2
                          + w3 * b0 + w4 * b1 + w5 * b2
                          + w6 * c0 + w7 * c1 + w8 * c2;
                op[step * 30] = acc;
                a0 = b0; a1 = b1; a2 = b2;
                b0 = c0; b1 = c1; b2 = c2;
            }
#undef TAP
        }
    }
    __syncthreads();

    // ---- stage C: u[r2][p] = sum_r1 t1[r1][p] * M[r1][r2], IN PLACE over st
    // thread owns 2 pixels for all 16 r2: reads all r1 at its pixels first,
    // writes after -> no cross-thread hazard. 450 threads.
    if (tid < 450) {
        const int p2 = tid * 2;
        float acc0[16], acc1[16];
#pragma unroll
        for (int r2 = 0; r2 < 16; ++r2) { acc0[r2] = 0.f; acc1[r2] = 0.f; }
#pragma unroll
        for (int r1 = 0; r1 < 16; ++r1) {
            float2 tv = *(const float2*)&st[r1 * 900 + p2];
#pragma unroll
            for (int q = 0; q < 4; ++q) {
                float4 mv = *(const float4*)&sM[r1 * 16 + q * 4];
                acc0[q * 4 + 0] += mv.x * tv.x;  acc1[q * 4 + 0] += mv.x * tv.y;
                acc0[q * 4 + 1] += mv.y * tv.x;  acc1[q * 4 + 1] += mv.y * tv.y;
                acc0[q * 4 + 2] += mv.z * tv.x;  acc1[q * 4 + 2] += mv.z * tv.y;
                acc0[q * 4 + 3] += mv.w * tv.x;  acc1[q * 4 + 3] += mv.w * tv.y;
            }
        }
#pragma unroll
        for (int r2 = 0; r2 < 16; ++r2)
            *(float2*)&st[r2 * 900 + p2] = make_float2(acc0[r2], acc1[r2]);
    }
    __syncthreads();

    // ---- stage D: t2[r2] = conv3x3(u[r2], w2[r2]) dotted into logits on
    // the fly: acc[n] += t2val * Wc2[n][r2*784 + o]   (no t2 buffer)
    float acc[10];
#pragma unroll
    for (int n = 0; n < 10; ++n) acc[n] = 0.f;
    {
        const int r2 = tid >> 6;
        const int s = tid & 63;
        const int col = s & 31;
        const int half = s >> 5;
        if (col < 28) {
            const float* wp = &sw2[r2 * 9];
            float w0 = wp[0], w1 = wp[1], w2 = wp[2];
            float w3 = wp[3], w4 = wp[4], w5 = wp[5];
            float w6 = wp[6], w7 = wp[7], w8 = wp[8];
            const int ho0 = half * 14;
            const float* base = &st[r2 * 900 + ho0 * 30 + col];
            float a0 = base[0],  a1 = base[1],  a2 = base[2];
            float b0 = base[30], b1 = base[31], b2 = base[32];
            const float* wc = &Wc2[r2 * 784 + ho0 * 28 + col];
#pragma unroll
            for (int step = 0; step < 14; ++step) {
                const float* rp = base + (step + 2) * 30;
                float c0 = rp[0], c1 = rp[1], c2 = rp[2];
                float v = w0 * a0 + w1 * a1 + w2 * a2
                        + w3 * b0 + w4 * b1 + w5 * b2
                        + w6 * c0 + w7 * c1 + w8 * c2;
                const float* wq = wc + step * 28;
#pragma unroll
                for (int n = 0; n < 10; ++n)
                    acc[n] += v * wq[n * 12544];
                a0 = b0; a1 = b1; a2 = b2;
                b0 = c0; b1 = c1; b2 = c2;
            }
        }
    }

    // ---- reduction + log_softmax ----
#pragma unroll
    for (int n = 0; n < 10; ++n) {
        float v = acc[n];
        for (int off = 32; off > 0; off >>= 1)
            v += __shfl_down(v, off, 64);
        if ((tid & 63) == 0) sred[(tid >> 6) * 10 + n] = v;
    }
    __syncthreads();
    if (tid < 10) {
        float lg = b_cls[tid];
#pragma unroll
        for (int w = 0; w < 16; ++w) lg += sred[w * 10 + tid];
        slog[tid] = lg;
    }
    __syncthreads();
    if (tid < 10) {
        float m = -1e30f;
#pragma unroll
        for (int n = 0; n < 10; ++n) m = fmaxf(m, slog[n]);
        float ssum = 0.f;
#pragma unroll
        for (int n = 0; n < 10; ++n) ssum += expf(slog[n] - m);
        out[b * 10 + tid] = slog[tid] - m - logf(ssum);
    }
}

extern "C" void kernel_launch(void* const* d_in, const int* in_sizes, int n_in,
                              void* d_out, int out_size, void* d_ws, size_t ws_size,
                              hipStream_t stream) {
    const float* x     = (const float*)d_in[0];
    const float* l1_f0 = (const float*)d_in[1];
    const float* l1_f1 = (const float*)d_in[2];
    const float* l1_f2 = (const float*)d_in[3];
    const float* l1_f3 = (const float*)d_in[4];
    const float* l2_f0 = (const float*)d_in[5];
    const float* l2_f1 = (const float*)d_in[6];
    const float* l2_f2 = (const float*)d_in[7];
    const float* l2_f3 = (const float*)d_in[8];
    const float* Wcls  = (const float*)d_in[9];
    const float* bcls  = (const float*)d_in[10];
    float* out = (float*)d_out;

    float* Wc2 = (float*)d_ws;                 // 10*16*784 floats
    float* Mm  = Wc2 + 10 * 16 * 784;          // 256 floats

    precomp_kernel<<<dim3((10 * 16 * 784 + 255) / 256), dim3(256), 0, stream>>>(
        l1_f0, l2_f0, l2_f3, Wcls, Wc2, Mm);
    fused_kernel<<<dim3(512), dim3(NT), 0, stream>>>(
        x, l1_f1, l1_f2, l1_f3, l2_f1, l2_f2, Wc2, Mm, bcls, out);
}

// Round 2
// 223.771 us; speedup vs baseline: 1.0124x; 1.0124x over previous
//
#include <hip/hip_runtime.h>
#include <math.h>

// x: (512, 3, 32, 32) fp32
// layer1: C=3 -> F=32, R=16, 3x3  -> (512,32,30,30)
// layer2: C=32 -> F=32, R=16, 3x3 -> (512,32,28,28)
// classifier: 25088 -> 10, then log_softmax
//
// Algebraic fusion (h1, h2 never materialized):
//   M[r1][r2]      = sum_f l1_f0[f][r1] * l2_f3[f][r2]            (16x16)
//   Wc2[n][r2][q]  = sum_f l2_f0[f][r2] * W_cls[n][f*784+q]       (10x16x784)
//
// LDS ~75KB -> 2 blocks/CU co-reside (all 512 blocks resident; barrier
// stalls of one block hide under the other).
// Round-2 fix: round-1's __launch_bounds__(1024,8) forced VGPR_Count=32 ->
// scratch spills (FETCH 172MB / WRITE 337MB of pure spill traffic). Now:
//   - amdgpu_waves_per_eu(8,8): exact semantics, VGPR budget 64.
//   - stage C: 1 pixel x 16 r2 per thread (16 accs, was 32) -> peak
//     register demand ~50, fits 64 without spills.

#define NT 1024

__global__ void precomp_kernel(const float* __restrict__ l1_f0,
                               const float* __restrict__ l2_f0,
                               const float* __restrict__ l2_f3,
                               const float* __restrict__ Wcls,
                               float* __restrict__ Wc2,
                               float* __restrict__ Mm) {
    int id = blockIdx.x * blockDim.x + threadIdx.x;
    if (id < 10 * 16 * 784) {
        int n = id / (16 * 784);
        int rem = id - n * (16 * 784);
        int r2 = rem / 784;
        int pix = rem - r2 * 784;
        float acc = 0.f;
#pragma unroll
        for (int f = 0; f < 32; ++f)
            acc += l2_f0[f * 16 + r2] * Wcls[n * 25088 + f * 784 + pix];
        Wc2[id] = acc;
    }
    if (id < 256) {
        int r1 = id >> 4, r2 = id & 15;
        float acc = 0.f;
#pragma unroll
        for (int f = 0; f < 32; ++f)
            acc += l1_f0[f * 16 + r1] * l2_f3[f * 16 + r2];
        Mm[id] = acc;
    }
}

__global__ __launch_bounds__(NT)
__attribute__((amdgpu_waves_per_eu(8, 8)))
void fused_kernel(
    const float* __restrict__ x,
    const float* __restrict__ l1_f1, const float* __restrict__ l1_f2,
    const float* __restrict__ l1_f3,
    const float* __restrict__ l2_f1, const float* __restrict__ l2_f2,
    const float* __restrict__ Wc2, const float* __restrict__ Mm,
    const float* __restrict__ b_cls,
    float* __restrict__ out) {
    __shared__ float4 sx[1024];      // 16 KB: (x0,x1,x2,-) per pixel
    __shared__ float st[16 * 900];   // 57.6 KB: t1, then u in place
    __shared__ float sw1[144];
    __shared__ float sw2[144];
    __shared__ float sf3[48];
    __shared__ float sM[256];        // M (16x16), row-major [r1][r2]
    __shared__ float sred[16 * 10];
    __shared__ float slog[10];

    const int tid = threadIdx.x;
    const int b = blockIdx.x;

    // ---- stage A: x -> LDS (pixel-major float4) + small weights ----
    {
        const float* xb = x + b * 3072;
        float x0 = xb[tid];
        float x1 = xb[1024 + tid];
        float x2 = xb[2048 + tid];
        sx[tid] = make_float4(x0, x1, x2, 0.f);
    }
    if (tid < 48) sf3[tid] = l1_f3[tid];
    if (tid >= 64 && tid < 208) {
        int t = tid - 64;
        int r = t / 9, ij = t - r * 9;
        int i = ij / 3, j = ij - i * 3;
        sw1[t] = l1_f1[i * 16 + r] * l1_f2[j * 16 + r];
    }
    if (tid >= 256 && tid < 400) {
        int t = tid - 256;
        int r = t / 9, ij = t - r * 9;
        int i = ij / 3, j = ij - i * 3;
        sw2[t] = l2_f1[i * 16 + r] * l2_f2[j * 16 + r];
    }
    if (tid >= 512 && tid < 768) sM[tid - 512] = Mm[tid - 512];
    __syncthreads();

    // ---- stage B: t1[r][ho][wo] = conv3x3( sum_c x[c]*f3[c][r] , w1[r] )
    // s1 taps computed on the fly from sx (rolling window: 3 new taps/step)
    {
        const int r = tid >> 6;
        const int s = tid & 63;
        const int col = s & 31;
        const int half = s >> 5;
        if (col < 30) {
            const float f30 = sf3[r], f31 = sf3[16 + r], f32 = sf3[32 + r];
            const float* wp = &sw1[r * 9];
            float w0 = wp[0], w1 = wp[1], w2 = wp[2];
            float w3 = wp[3], w4 = wp[4], w5 = wp[5];
            float w6 = wp[6], w7 = wp[7], w8 = wp[8];
            const int ho0 = half * 15;
            const float4* xb = &sx[ho0 * 32 + col];
#define TAP(idx) ({ float4 _v = xb[(idx)]; _v.x * f30 + _v.y * f31 + _v.z * f32; })
            float a0 = TAP(0),  a1 = TAP(1),  a2 = TAP(2);
            float b0 = TAP(32), b1 = TAP(33), b2 = TAP(34);
            float* op = &st[r * 900 + ho0 * 30 + col];
#pragma unroll
            for (int step = 0; step < 15; ++step) {
                const int nb = (step + 2) * 32;
                float c0 = TAP(nb), c1 = TAP(nb + 1), c2 = TAP(nb + 2);
                float acc = w0 * a0 + w1 * a1 + w2 * a2
                          + w3 * b0 + w4 * b1 + w5 * b2
                          + w6 * c0 + w7 * c1 + w8 * c2;
                op[step * 30] = acc;
                a0 = b0; a1 = b1; a2 = b2;
                b0 = c0; b1 = c1; b2 = c2;
            }
#undef TAP
        }
    }
    __syncthreads();

    // ---- stage C: u[r2][p] = sum_r1 t1[r1][p] * M[r1][r2], IN PLACE over st
    // 1 pixel x 16 r2 per thread (16 accs; column-exclusive -> no hazard)
    if (tid < 900) {
        const int p = tid;
        float acc[16];
#pragma unroll
        for (int r2 = 0; r2 < 16; ++r2) acc[r2] = 0.f;
#pragma unroll
        for (int r1 = 0; r1 < 16; ++r1) {
            float tv = st[r1 * 900 + p];
#pragma unroll
            for (int q = 0; q < 4; ++q) {
                float4 mv = *(const float4*)&sM[r1 * 16 + q * 4];
                acc[q * 4 + 0] += mv.x * tv;
                acc[q * 4 + 1] += mv.y * tv;
                acc[q * 4 + 2] += mv.z * tv;
                acc[q * 4 + 3] += mv.w * tv;
            }
        }
#pragma unroll
        for (int r2 = 0; r2 < 16; ++r2)
            st[r2 * 900 + p] = acc[r2];
    }
    __syncthreads();

    // ---- stage D: t2[r2] = conv3x3(u[r2], w2[r2]) dotted into logits on
    // the fly: acc[n] += t2val * Wc2[n][r2*784 + o]   (no t2 buffer)
    float acc[10];
#pragma unroll
    for (int n = 0; n < 10; ++n) acc[n] = 0.f;
    {
        const int r2 = tid >> 6;
        const int s = tid & 63;
        const int col = s & 31;
        const int half = s >> 5;
        if (col < 28) {
            const float* wp = &sw2[r2 * 9];
            float w0 = wp[0], w1 = wp[1], w2 = wp[2];
            float w3 = wp[3], w4 = wp[4], w5 = wp[5];
            float w6 = wp[6], w7 = wp[7], w8 = wp[8];
            const int ho0 = half * 14;
            const float* base = &st[r2 * 900 + ho0 * 30 + col];
            float a0 = base[0],  a1 = base[1],  a2 = base[2];
            float b0 = base[30], b1 = base[31], b2 = base[32];
            const float* wc = &Wc2[r2 * 784 + ho0 * 28 + col];
#pragma unroll
            for (int step = 0; step < 14; ++step) {
                const float* rp = base + (step + 2) * 30;
                float c0 = rp[0], c1 = rp[1], c2 = rp[2];
                float v = w0 * a0 + w1 * a1 + w2 * a2
                        + w3 * b0 + w4 * b1 + w5 * b2
                        + w6 * c0 + w7 * c1 + w8 * c2;
                const float* wq = wc + step * 28;
#pragma unroll
                for (int n = 0; n < 10; ++n)
                    acc[n] += v * wq[n * 12544];
                a0 = b0; a1 = b1; a2 = b2;
                b0 = c0; b1 = c1; b2 = c2;
            }
        }
    }

    // ---- reduction + log_softmax ----
#pragma unroll
    for (int n = 0; n < 10; ++n) {
        float v = acc[n];
        for (int off = 32; off > 0; off >>= 1)
            v += __shfl_down(v, off, 64);
        if ((tid & 63) == 0) sred[(tid >> 6) * 10 + n] = v;
    }
    __syncthreads();
    if (tid < 10) {
        float lg = b_cls[tid];
#pragma unroll
        for (int w = 0; w < 16; ++w) lg += sred[w * 10 + tid];
        slog[tid] = lg;
    }
    __syncthreads();
    if (tid < 10) {
        float m = -1e30f;
#pragma unroll
        for (int n = 0; n < 10; ++n) m = fmaxf(m, slog[n]);
        float ssum = 0.f;
#pragma unroll
        for (int n = 0; n < 10; ++n) ssum += expf(slog[n] - m);
        out[b * 10 + tid] = slog[tid] - m - logf(ssum);
    }
}

extern "C" void kernel_launch(void* const* d_in, const int* in_sizes, int n_in,
                              void* d_out, int out_size, void* d_ws, size_t ws_size,
                              hipStream_t stream) {
    const float* x     = (const float*)d_in[0];
    const float* l1_f0 = (const float*)d_in[1];
    const float* l1_f1 = (const float*)d_in[2];
    const float* l1_f2 = (const float*)d_in[3];
    const float* l1_f3 = (const float*)d_in[4];
    const float* l2_f0 = (const float*)d_in[5];
    const float* l2_f1 = (const float*)d_in[6];
    const float* l2_f2 = (const float*)d_in[7];
    const float* l2_f3 = (const float*)d_in[8];
    const float* Wcls  = (const float*)d_in[9];
    const float* bcls  = (const float*)d_in[10];
    float* out = (float*)d_out;

    float* Wc2 = (float*)d_ws;                 // 10*16*784 floats
    float* Mm  = Wc2 + 10 * 16 * 784;          // 256 floats

    precomp_kernel<<<dim3((10 * 16 * 784 + 255) / 256), dim3(256), 0, stream>>>(
        l1_f0, l2_f0, l2_f3, Wcls, Wc2, Mm);
    fused_kernel<<<dim3(512), dim3(NT), 0, stream>>>(
        x, l1_f1, l1_f2, l1_f3, l2_f1, l2_f2, Wc2, Mm, bcls, out);
}

// Round 3
// 124.871 us; speedup vs baseline: 1.8143x; 1.7920x over previous
//
#include <hip/hip_runtime.h>
#include <math.h>

// x: (512, 3, 32, 32) fp32
// layer1: C=3 -> F=32, R=16, 3x3  -> (512,32,30,30)
// layer2: C=32 -> F=32, R=16, 3x3 -> (512,32,28,28)
// classifier: 25088 -> 10, then log_softmax
//
// Algebraic fusion (h1, h2 never materialized):
//   M[r1][r2]      = sum_f l1_f0[f][r1] * l2_f3[f][r2]            (16x16)
//   Wc2[n][r2][q]  = sum_f l2_f0[f][r2] * W_cls[n][f*784+q]       (10x16x784)
//   cw1[r1][ij]    = l1_f1[i][r1] * l1_f2[j][r1]                  (16x9)
//   cw2[r2][ij]    = l2_f1[i][r2] * l2_f2[j][r2]                  (16x9)
//
// Round-3 restructure: the 1024-thread megakernel was barrier-convoy bound
// at 1 block/CU, and forcing 2 blocks/CU collapsed VGPRs to 32 -> 450MB of
// spill traffic (rounds 1-2). Split into a pipeline with a global
// intermediate u = M-contracted conv1 output (512x16x900, 29.5 MB in ws):
//   conv1_kernel: thread = output pixel. 27 x loads -> t1[r1] on the fly ->
//     M-contract -> 16 stores. ZERO LDS, ZERO barriers, ~50 VGPR.
//   conv2_cls_kernel: rolling-column conv2 reading u direct from global
//     (L2-resident), dotted into logits on the fly; 2 images/block so each
//     Wc2 load feeds 2 FMAs. LDS ~1KB, 2 barriers (reduction+softmax).

__global__ void precomp_kernel(const float* __restrict__ l1_f0,
                               const float* __restrict__ l1_f1,
                               const float* __restrict__ l1_f2,
                               const float* __restrict__ l2_f0,
                               const float* __restrict__ l2_f1,
                               const float* __restrict__ l2_f2,
                               const float* __restrict__ l2_f3,
                               const float* __restrict__ Wcls,
                               float* __restrict__ Wc2,
                               float* __restrict__ Mm,
                               float* __restrict__ cw1,
                               float* __restrict__ cw2) {
    int id = blockIdx.x * blockDim.x + threadIdx.x;
    if (id < 10 * 16 * 784) {
        int n = id / (16 * 784);
        int rem = id - n * (16 * 784);
        int r2 = rem / 784;
        int pix = rem - r2 * 784;
        float acc = 0.f;
#pragma unroll
        for (int f = 0; f < 32; ++f)
            acc += l2_f0[f * 16 + r2] * Wcls[n * 25088 + f * 784 + pix];
        Wc2[id] = acc;
    }
    if (id < 256) {
        int r1 = id >> 4, r2 = id & 15;
        float acc = 0.f;
#pragma unroll
        for (int f = 0; f < 32; ++f)
            acc += l1_f0[f * 16 + r1] * l2_f3[f * 16 + r2];
        Mm[id] = acc;
    }
    if (id >= 256 && id < 400) {
        int t = id - 256;
        int r = t / 9, ij = t - r * 9;
        int i = ij / 3, j = ij - i * 3;
        cw1[t] = l1_f1[i * 16 + r] * l1_f2[j * 16 + r];
    }
    if (id >= 400 && id < 544) {
        int t = id - 400;
        int r = t / 9, ij = t - r * 9;
        int i = ij / 3, j = ij - i * 3;
        cw2[t] = l2_f1[i * 16 + r] * l2_f2[j * 16 + r];
    }
}

// ---- kernel A: u[b][r2][p] = sum_r1 M[r1][r2] * conv3x3(s1[r1])[p] ----
// thread = one output pixel of one image. No LDS, no barriers.
__global__ __launch_bounds__(256) void conv1_kernel(
    const float* __restrict__ x,
    const float* __restrict__ Mm,    // [r1][r2] 16x16
    const float* __restrict__ cw1,   // [r1][9]
    const float* __restrict__ f3,    // l1_f3: [c][r1] (c*16+r1)
    float* __restrict__ u) {
    const int p = blockIdx.x * 256 + threadIdx.x;   // 0..1023
    const int b = blockIdx.y;
    if (p >= 900) return;
    const int ho = p / 30;
    const int wo = p - ho * 30;
    const float* xb = x + b * 3072 + ho * 32 + wo;

    float xv0[9], xv1[9], xv2[9];
#pragma unroll
    for (int i = 0; i < 3; ++i)
#pragma unroll
        for (int j = 0; j < 3; ++j) {
            xv0[i * 3 + j] = xb[i * 32 + j];
            xv1[i * 3 + j] = xb[1024 + i * 32 + j];
            xv2[i * 3 + j] = xb[2048 + i * 32 + j];
        }

    float uacc[16];
#pragma unroll
    for (int r2 = 0; r2 < 16; ++r2) uacc[r2] = 0.f;

    for (int r1 = 0; r1 < 16; ++r1) {
        const float f0 = f3[r1], f1 = f3[16 + r1], f2 = f3[32 + r1];
        float t1 = 0.f;
#pragma unroll
        for (int ij = 0; ij < 9; ++ij)
            t1 += cw1[r1 * 9 + ij] * (xv0[ij] * f0 + xv1[ij] * f1 + xv2[ij] * f2);
#pragma unroll
        for (int r2 = 0; r2 < 16; ++r2)
            uacc[r2] += t1 * Mm[r1 * 16 + r2];
    }

    float* ub = u + b * 14400;
#pragma unroll
    for (int r2 = 0; r2 < 16; ++r2)
        ub[r2 * 900 + p] = uacc[r2];
}

// ---- kernel B: logits[n] = b[n] + sum_{r2,o} conv3x3(u[r2])[o] * Wc2[n][r2][o]
// 1024 threads = 16 r2-planes x (28 cols x 2 halves). 2 images per block.
// u read directly from global (L2-resident), rolling window down columns.
__global__ __launch_bounds__(1024) void conv2_cls_kernel(
    const float* __restrict__ u,     // [b][r2][900]
    const float* __restrict__ cw2,   // [r2][9]
    const float* __restrict__ Wc2,   // [n][r2][784]
    const float* __restrict__ b_cls,
    float* __restrict__ out) {
    __shared__ float sred[2][16][10];
    __shared__ float slog[2][10];

    const int tid = threadIdx.x;
    const int b0 = blockIdx.x * 2;
    const int r2 = tid >> 6;
    const int s = tid & 63;
    const int col = s & 31;
    const int half = s >> 5;

    float acc0[10], acc1[10];
#pragma unroll
    for (int n = 0; n < 10; ++n) { acc0[n] = 0.f; acc1[n] = 0.f; }

    if (col < 28) {
        const float* wp = &cw2[r2 * 9];
        const float w0 = wp[0], w1 = wp[1], w2 = wp[2];
        const float w3 = wp[3], w4 = wp[4], w5 = wp[5];
        const float w6 = wp[6], w7 = wp[7], w8 = wp[8];
        const int ho0 = half * 14;
        const float* base0 = u + b0 * 14400 + r2 * 900 + ho0 * 30 + col;
        const float* base1 = base0 + 14400;
        float a00 = base0[0],  a01 = base0[1],  a02 = base0[2];
        float b00 = base0[30], b01 = base0[31], b02 = base0[32];
        float a10 = base1[0],  a11 = base1[1],  a12 = base1[2];
        float b10 = base1[30], b11 = base1[31], b12 = base1[32];
        const float* wc = Wc2 + r2 * 784 + ho0 * 28 + col;
#pragma unroll
        for (int step = 0; step < 14; ++step) {
            const float* rp0 = base0 + (step + 2) * 30;
            const float* rp1 = base1 + (step + 2) * 30;
            float c00 = rp0[0], c01 = rp0[1], c02 = rp0[2];
            float c10 = rp1[0], c11 = rp1[1], c12 = rp1[2];
            float v0 = w0 * a00 + w1 * a01 + w2 * a02
                     + w3 * b00 + w4 * b01 + w5 * b02
                     + w6 * c00 + w7 * c01 + w8 * c02;
            float v1 = w0 * a10 + w1 * a11 + w2 * a12
                     + w3 * b10 + w4 * b11 + w5 * b12
                     + w6 * c10 + w7 * c11 + w8 * c12;
            const float* wq = wc + step * 28;
#pragma unroll
            for (int n = 0; n < 10; ++n) {
                float wn = wq[n * 12544];
                acc0[n] += v0 * wn;
                acc1[n] += v1 * wn;
            }
            a00 = b00; a01 = b01; a02 = b02;
            b00 = c00; b01 = c01; b02 = c02;
            a10 = b10; a11 = b11; a12 = b12;
            b10 = c10; b11 = c11; b12 = c12;
        }
    }

    // ---- per-wave reduce (wave id == r2), then cross-wave in LDS ----
#pragma unroll
    for (int n = 0; n < 10; ++n) {
        float v = acc0[n];
        for (int off = 32; off > 0; off >>= 1)
            v += __shfl_down(v, off, 64);
        if (s == 0) sred[0][r2][n] = v;
        float w = acc1[n];
        for (int off = 32; off > 0; off >>= 1)
            w += __shfl_down(w, off, 64);
        if (s == 0) sred[1][r2][n] = w;
    }
    __syncthreads();

    if (tid < 10) {
        float lg = b_cls[tid];
#pragma unroll
        for (int w = 0; w < 16; ++w) lg += sred[0][w][tid];
        slog[0][tid] = lg;
    } else if (tid >= 64 && tid < 74) {
        int n = tid - 64;
        float lg = b_cls[n];
#pragma unroll
        for (int w = 0; w < 16; ++w) lg += sred[1][w][n];
        slog[1][n] = lg;
    }
    __syncthreads();

    if (tid < 10) {
        float m = -1e30f;
#pragma unroll
        for (int n = 0; n < 10; ++n) m = fmaxf(m, slog[0][n]);
        float ssum = 0.f;
#pragma unroll
        for (int n = 0; n < 10; ++n) ssum += expf(slog[0][n] - m);
        out[b0 * 10 + tid] = slog[0][tid] - m - logf(ssum);
    } else if (tid >= 64 && tid < 74) {
        int n = tid - 64;
        float m = -1e30f;
#pragma unroll
        for (int k = 0; k < 10; ++k) m = fmaxf(m, slog[1][k]);
        float ssum = 0.f;
#pragma unroll
        for (int k = 0; k < 10; ++k) ssum += expf(slog[1][k] - m);
        out[(b0 + 1) * 10 + n] = slog[1][n] - m - logf(ssum);
    }
}

extern "C" void kernel_launch(void* const* d_in, const int* in_sizes, int n_in,
                              void* d_out, int out_size, void* d_ws, size_t ws_size,
                              hipStream_t stream) {
    const float* x     = (const float*)d_in[0];
    const float* l1_f0 = (const float*)d_in[1];
    const float* l1_f1 = (const float*)d_in[2];
    const float* l1_f2 = (const float*)d_in[3];
    const float* l1_f3 = (const float*)d_in[4];
    const float* l2_f0 = (const float*)d_in[5];
    const float* l2_f1 = (const float*)d_in[6];
    const float* l2_f2 = (const float*)d_in[7];
    const float* l2_f3 = (const float*)d_in[8];
    const float* Wcls  = (const float*)d_in[9];
    const float* bcls  = (const float*)d_in[10];
    float* out = (float*)d_out;

    float* Wc2 = (float*)d_ws;                 // 125440 floats
    float* Mm  = Wc2 + 10 * 16 * 784;          // 256
    float* cw1 = Mm + 256;                     // 144
    float* cw2 = cw1 + 144;                    // 144
    float* u   = cw2 + 144;                    // 512*16*900 = 7,372,800 floats (29.5 MB)

    precomp_kernel<<<dim3((10 * 16 * 784 + 255) / 256), dim3(256), 0, stream>>>(
        l1_f0, l1_f1, l1_f2, l2_f0, l2_f1, l2_f2, l2_f3, Wcls, Wc2, Mm, cw1, cw2);
    conv1_kernel<<<dim3(4, 512), dim3(256), 0, stream>>>(x, Mm, cw1, l1_f3, u);
    conv2_cls_kernel<<<dim3(256), dim3(1024), 0, stream>>>(u, cw2, Wc2, bcls, out);
}

// Round 4
// 93.043 us; speedup vs baseline: 2.4350x; 1.3421x over previous
//
#include <hip/hip_runtime.h>
#include <math.h>

// KEY INSIGHT: the reference network is ENTIRELY LINEAR before log_softmax
// (two decomposed conv layers with no activation, then a linear classifier).
// The whole model collapses to one linear map:
//     logits[b,n] = b_cls[n] + <x[b,:,:,:], Wx[n,:,:,:]>,  Wx: (10,3,32,32)
// Wx is folded from the weights by pushing the classifier backward through
// both convs (transposed-conv / full-correlation chain):
//   cw1[r1,ij] = l1_f1[i,r1]*l1_f2[j,r1];  cw2[r2,ij] = l2_f1[i,r2]*l2_f2[j,r2]
//   M[r1,r2]   = sum_f l1_f0[f,r1]*l2_f3[f,r2]
//   Wc2[n,r2,q784]  = sum_f l2_f0[f,r2]*W_cls[n,f*784+q]
//   Wc3[n,r2,h,w30] = sum_{ij: 0<=h-i<28, 0<=w-j<28} cw2[r2,ij]*Wc2[n,r2,h-i,w-j]
//   K[c,ij,r2]      = sum_r1 l1_f3[c,r1]*cw1[r1,ij]*M[r1,r2]
//   Wx[n,c,H,W32]   = sum_{ij: 0<=H-i<30, 0<=W-j<30} sum_r2 K[c,ij,r2]*Wc3[n,r2,H-i,W-j]
// Precompute ~50M FMA (1-2us); main pass reads only x (6.3MB) + Wx (120KB).

// ---- P1: Wc3 (blocks 0..159 = (n,r2)), M + K (block 160) ----
__global__ __launch_bounds__(256) void precomp1(
    const float* __restrict__ l1_f0, const float* __restrict__ l1_f1,
    const float* __restrict__ l1_f2, const float* __restrict__ l1_f3,
    const float* __restrict__ l2_f0, const float* __restrict__ l2_f1,
    const float* __restrict__ l2_f2, const float* __restrict__ l2_f3,
    const float* __restrict__ Wcls,
    float* __restrict__ Wc3, float* __restrict__ Kc) {
    __shared__ float sWc2[784];
    __shared__ float sM[256];
    const int tid = threadIdx.x;
    const int blk = blockIdx.x;

    if (blk < 160) {
        const int n = blk >> 4, r2 = blk & 15;
        // Wc2[n,r2,:] -> LDS
        for (int q = tid; q < 784; q += 256) {
            float acc = 0.f;
#pragma unroll
            for (int f = 0; f < 32; ++f)
                acc += l2_f0[f * 16 + r2] * Wcls[n * 25088 + f * 784 + q];
            sWc2[q] = acc;
        }
        __syncthreads();
        float cw[9];
#pragma unroll
        for (int ij = 0; ij < 9; ++ij) {
            int i = ij / 3, j = ij - (ij / 3) * 3;
            cw[ij] = l2_f1[i * 16 + r2] * l2_f2[j * 16 + r2];
        }
        // full-correlation: Wc3[h,w] = sum_{ij valid} cw[ij]*Wc2[h-i,w-j]
        for (int p = tid; p < 900; p += 256) {
            int h = p / 30, w = p - (p / 30) * 30;
            float acc = 0.f;
#pragma unroll
            for (int i = 0; i < 3; ++i) {
                int hh = h - i;
                if (hh < 0 || hh > 27) continue;
#pragma unroll
                for (int j = 0; j < 3; ++j) {
                    int ww = w - j;
                    if (ww < 0 || ww > 27) continue;
                    acc += cw[i * 3 + j] * sWc2[hh * 28 + ww];
                }
            }
            Wc3[blk * 900 + p] = acc;
        }
    } else {
        // M[r1,r2] then K[c,ij,r2]
        {
            int r1 = tid >> 4, r2 = tid & 15;
            float acc = 0.f;
#pragma unroll
            for (int f = 0; f < 32; ++f)
                acc += l1_f0[f * 16 + r1] * l2_f3[f * 16 + r2];
            sM[tid] = acc;
        }
        __syncthreads();
        for (int t = tid; t < 432; t += 256) {
            int c = t / 144;
            int rem = t - c * 144;
            int ij = rem >> 4;
            int r2 = rem & 15;
            int i = ij / 3, j = ij - i * 3;
            float acc = 0.f;
#pragma unroll
            for (int r1 = 0; r1 < 16; ++r1) {
                float cw1v = l1_f1[i * 16 + r1] * l1_f2[j * 16 + r1];
                acc += l1_f3[c * 16 + r1] * cw1v * sM[r1 * 16 + r2];
            }
            Kc[t] = acc;   // layout (c*9+ij)*16 + r2
        }
    }
}

// ---- P2: Wx[n,c,H,W] from Wc3 and K ----
__global__ __launch_bounds__(256) void precomp2(
    const float* __restrict__ Wc3, const float* __restrict__ Kc,
    float* __restrict__ Wx) {
    const int t = blockIdx.x * 256 + threadIdx.x;
    if (t >= 30720) return;
    const int n = t / 3072;
    const int rem = t - n * 3072;
    const int c = rem >> 10;
    const int p = rem & 1023;
    const int H = p >> 5, W = p & 31;
    const float* wn = Wc3 + n * 14400;
    float acc = 0.f;
#pragma unroll
    for (int i = 0; i < 3; ++i) {
        int hh = H - i;
        if (hh < 0 || hh >= 30) continue;
#pragma unroll
        for (int j = 0; j < 3; ++j) {
            int ww = W - j;
            if (ww < 0 || ww >= 30) continue;
            const float* wp = wn + hh * 30 + ww;
            const float* kp = Kc + (c * 9 + i * 3 + j) * 16;
#pragma unroll
            for (int r2 = 0; r2 < 16; ++r2)
                acc += kp[r2] * wp[r2 * 900];
        }
    }
    Wx[t] = acc;   // t = n*3072 + c*1024 + p  (matches x's (c,H,W) layout)
}

// ---- P3: logits = x . Wx^T + b, then log_softmax. One block per image ----
__global__ __launch_bounds__(256) void cls_kernel(
    const float* __restrict__ x, const float* __restrict__ Wx,
    const float* __restrict__ b_cls, float* __restrict__ out) {
    __shared__ float sred[4][10];
    __shared__ float slog[10];
    const int tid = threadIdx.x;
    const int b = blockIdx.x;
    const float4* xb = (const float4*)(x + b * 3072);
    const float4* wx4 = (const float4*)Wx;

    float acc[10];
#pragma unroll
    for (int n = 0; n < 10; ++n) acc[n] = 0.f;
#pragma unroll
    for (int k = 0; k < 3; ++k) {
        const int idx = tid + k * 256;      // 0..767 float4 chunks
        float4 xv = xb[idx];
#pragma unroll
        for (int n = 0; n < 10; ++n) {
            float4 wv = wx4[n * 768 + idx];
            acc[n] += xv.x * wv.x + xv.y * wv.y + xv.z * wv.z + xv.w * wv.w;
        }
    }

    const int lane = tid & 63, wid = tid >> 6;
#pragma unroll
    for (int n = 0; n < 10; ++n) {
        float v = acc[n];
        for (int off = 32; off > 0; off >>= 1)
            v += __shfl_down(v, off, 64);
        if (lane == 0) sred[wid][n] = v;
    }
    __syncthreads();
    if (tid < 10) {
        slog[tid] = b_cls[tid] + sred[0][tid] + sred[1][tid]
                  + sred[2][tid] + sred[3][tid];
    }
    __syncthreads();
    if (tid < 10) {
        float m = -1e30f;
#pragma unroll
        for (int n = 0; n < 10; ++n) m = fmaxf(m, slog[n]);
        float ssum = 0.f;
#pragma unroll
        for (int n = 0; n < 10; ++n) ssum += expf(slog[n] - m);
        out[b * 10 + tid] = slog[tid] - m - logf(ssum);
    }
}

extern "C" void kernel_launch(void* const* d_in, const int* in_sizes, int n_in,
                              void* d_out, int out_size, void* d_ws, size_t ws_size,
                              hipStream_t stream) {
    const float* x     = (const float*)d_in[0];
    const float* l1_f0 = (const float*)d_in[1];
    const float* l1_f1 = (const float*)d_in[2];
    const float* l1_f2 = (const float*)d_in[3];
    const float* l1_f3 = (const float*)d_in[4];
    const float* l2_f0 = (const float*)d_in[5];
    const float* l2_f1 = (const float*)d_in[6];
    const float* l2_f2 = (const float*)d_in[7];
    const float* l2_f3 = (const float*)d_in[8];
    const float* Wcls  = (const float*)d_in[9];
    const float* bcls  = (const float*)d_in[10];
    float* out = (float*)d_out;

    float* Wc3 = (float*)d_ws;          // 10*16*900 = 144000 floats (576 KB)
    float* Kc  = Wc3 + 144000;          // 432 floats
    float* Wx  = Kc + 432;              // 10*3*1024 = 30720 floats (120 KB)

    precomp1<<<dim3(161), dim3(256), 0, stream>>>(
        l1_f0, l1_f1, l1_f2, l1_f3, l2_f0, l2_f1, l2_f2, l2_f3, Wcls, Wc3, Kc);
    precomp2<<<dim3(120), dim3(256), 0, stream>>>(Wc3, Kc, Wx);
    cls_kernel<<<dim3(512), dim3(256), 0, stream>>>(x, Wx, bcls, out);
}